// Round 6
// baseline (296.985 us; speedup 1.0000x reference)
//
#include <hip/hip_runtime.h>
#include <hip/hip_bf16.h>

typedef unsigned short u16;
typedef __bf16 bf16x8 __attribute__((ext_vector_type(8)));
typedef short s16x4 __attribute__((ext_vector_type(4)));
typedef float f32x4 __attribute__((ext_vector_type(4)));

__device__ __forceinline__ f32x4 mfma16(bf16x8 a, bf16x8 b, f32x4 c) {
    return __builtin_amdgcn_mfma_f32_16x16x32_bf16(a, b, c, 0, 0, 0);
}
__device__ __forceinline__ f32x4 mfma16k16(s16x4 a, s16x4 b, f32x4 c) {
    return __builtin_amdgcn_mfma_f32_16x16x16bf16_1k(a, b, c, 0, 0, 0);
}

// fp32 -> bf16 bits, round-to-nearest-even
__device__ __forceinline__ u16 f2b(float x) {
    union { float f; unsigned u; } a; a.f = x;
    unsigned r = a.u + 0x7fffu + ((a.u >> 16) & 1u);
    return (u16)(r >> 16);
}
// packed pair (RTNE, identical result to f2b per element)
__device__ __forceinline__ unsigned f2b2(float a, float b) {
    union { __hip_bfloat162 h; unsigned u; } cv;
    cv.h = __float22bfloat162_rn(make_float2(a, b));
    return cv.u;
}

// ---------------- fused cast fp32 -> bf16 for all three inputs ----------------
#define NX  (8192 * 512)
#define NWQ (1536 * 512)
#define NWO (512 * 512)
__global__ __launch_bounds__(256) void k_cast_all(const float* __restrict__ x,
                                                  const float* __restrict__ wq,
                                                  const float* __restrict__ wo,
                                                  u16* __restrict__ xb,
                                                  u16* __restrict__ wqb,
                                                  u16* __restrict__ wob) {
    int i = (blockIdx.x * 256 + threadIdx.x) * 4;
    const float* s; u16* d; int off;
    if (i < NX)            { s = x;  d = xb;  off = i; }
    else if (i < NX + NWQ) { s = wq; d = wqb; off = i - NX; }
    else                   { s = wo; d = wob; off = i - NX - NWQ; }
    float4 f = *(const float4*)&s[off];
    uint2 o = make_uint2(f2b2(f.x, f.y), f2b2(f.z, f.w));
    *(uint2*)&d[off] = o;
}

// ---------------- QKV GEMM: [8192,512]bf16 x [1536,512]bf16^T ----------------
// q,k -> [B*H][S][64] bf16 (q pre-scaled 0.125/ln2)
// v   -> VF[bh][kt][nt][mb][quad][l15][4]  (PV A-fragment order, perfectly coalesced)
__global__ __launch_bounds__(256) void k_gemm_qkv(const u16* __restrict__ xb,
                                                  const u16* __restrict__ wb,
                                                  const float* __restrict__ bias,
                                                  u16* __restrict__ qkvout) {
    __shared__ u16 As[128][40];
    __shared__ u16 Ws[128][40];
    const int tid = threadIdx.x;
    const int w = tid >> 6, lane = tid & 63, l15 = lane & 15, quad = lane >> 4;
    const int mb = blockIdx.x * 128, nb = blockIdx.y * 128;

    f32x4 acc[2][8];
#pragma unroll
    for (int i = 0; i < 2; i++)
#pragma unroll
        for (int j = 0; j < 8; j++) acc[i][j] = (f32x4){0.f, 0.f, 0.f, 0.f};

    for (int k0 = 0; k0 < 512; k0 += 32) {
        {
            int row = tid >> 1, cc = (tid & 1) * 16;
            const u16* g = &xb[(size_t)(mb + row) * 512 + k0 + cc];
            *(uint4*)&As[row][cc]     = *(const uint4*)g;
            *(uint4*)&As[row][cc + 8] = *(const uint4*)(g + 8);
            const u16* gw = &wb[(size_t)(nb + row) * 512 + k0 + cc];
            *(uint4*)&Ws[row][cc]     = *(const uint4*)gw;
            *(uint4*)&Ws[row][cc + 8] = *(const uint4*)(gw + 8);
        }
        __syncthreads();
        bf16x8 a0 = *(const bf16x8*)&As[w * 32 + l15][quad * 8];
        bf16x8 a1 = *(const bf16x8*)&As[w * 32 + 16 + l15][quad * 8];
#pragma unroll
        for (int nt = 0; nt < 8; nt++) {
            bf16x8 bfr = *(const bf16x8*)&Ws[nt * 16 + l15][quad * 8];
            acc[0][nt] = mfma16(a0, bfr, acc[0][nt]);
            acc[1][nt] = mfma16(a1, bfr, acc[1][nt]);
        }
        __syncthreads();
    }
    const int seg = nb >> 9;          // 0=q 1=k 2=v (128-tile stays in one seg)
    u16* obase = qkvout + (size_t)seg * (16ull * 4096 * 64);
    if (seg < 2) {
        const float sc = (seg == 0) ? 0.125f * 1.44269504088896340736f : 1.0f;
#pragma unroll
        for (int mt = 0; mt < 2; mt++)
#pragma unroll
            for (int nt = 0; nt < 8; nt++) {
                int dcol = nb + nt * 16 + l15;
                int hh = (dcol >> 6) & 7, dloc = dcol & 63;
                float bs = bias[dcol];
#pragma unroll
                for (int r = 0; r < 4; r++) {
                    int m = mb + w * 32 + mt * 16 + quad * 4 + r;
                    float vv = (acc[mt][nt][r] + bs) * sc;
                    int b = m >> 12, s = m & 4095;
                    obase[((size_t)((b * 8 + hh) * 4096 + s)) * 64 + dloc] = f2b(vv);
                }
            }
    } else {
        // V in PV-A-frag order: F4 = ((((bh*64+kt)*4+ntv)*4+mbv)*4+quad)*16+l15v, +r elementwise
#pragma unroll
        for (int mt = 0; mt < 2; mt++)
#pragma unroll
            for (int nt = 0; nt < 8; nt++) {
                int c = nb + nt * 16 + l15;
                int hh = (c >> 6) & 7, d = c & 63;
                int mbv = d >> 4, l15v = d & 15;
                float bs = bias[c];
                int m0 = mb + w * 32 + mt * 16 + quad * 4;
                int b = m0 >> 12, si = m0 & 4095;
                int kt = si >> 6, ka = si & 63;
                int ntv = ka >> 4;
                uint2 o = make_uint2(f2b2(acc[mt][nt][0] + bs, acc[mt][nt][1] + bs),
                                     f2b2(acc[mt][nt][2] + bs, acc[mt][nt][3] + bs));
                size_t F4 = ((((((size_t)(b * 8 + hh) * 64 + kt) * 4 + ntv) * 4 + mbv) * 4 + quad) * 16 + l15v);
                *(uint2*)&obase[F4 * 4] = o;
            }
    }
}

// ---------------- flash attention v6 (inverted-window mask) -----------------
// Barrier-free, LDS-free. 256 thr = 4 independent waves x 32 q-rows.
// K fragments load direct from global (row pattern = 16 full cache lines/inst);
// V fragments from fragment-ordered global; P stays in registers.
// Row-sums accumulate via a ones-row MFMA (matrix pipe, off the VALU chain).
__global__ __launch_bounds__(256) void k_attn(const u16* __restrict__ qkv,
                                              const u16* __restrict__ vfg,
                                              u16* __restrict__ ctx,
                                              const int* __restrict__ win) {
    const int tid = threadIdx.x;
    const int w = tid >> 6, lane = tid & 63, l15 = lane & 15, quad = lane >> 4;
    const int bh = blockIdx.y;
    const int qb0 = blockIdx.x * 128 + w * 32;   // this wave's 32 q-rows
    const int W = win[0];
    const u16* qg = qkv;
    const u16* kg = qkv + 16ull * 4096 * 64;
    const size_t bhb = (size_t)bh * 4096 * 64;

    // Q fragments: B-operand of S^T = K*Q^T
    bf16x8 qf[2][2];
#pragma unroll
    for (int g = 0; g < 2; g++) {
        const u16* qrow = &qg[bhb + (size_t)(qb0 + g * 16 + l15) * 64];
        qf[g][0] = *(const bf16x8*)&qrow[quad * 8];
        qf[g][1] = *(const bf16x8*)&qrow[32 + quad * 8];
    }

    // ones A-frag (row 0 = 1.0) for lsum-in-MFMA
    const short one_bf = (short)0x3F80;
    s16x4 onesA;
    {
        short v = (l15 == 0) ? one_bf : (short)0;
        onesA[0] = v; onesA[1] = v; onesA[2] = v; onesA[3] = v;
    }

    f32x4 O[2][4];
#pragma unroll
    for (int g = 0; g < 2; g++)
#pragma unroll
        for (int mb = 0; mb < 4; mb++) O[g][mb] = (f32x4){0.f, 0.f, 0.f, 0.f};
    f32x4 O1[2] = {(f32x4){0.f, 0.f, 0.f, 0.f}, (f32x4){0.f, 0.f, 0.f, 0.f}};

    // per-lane base pointers
    const u16* klp = &kg[bhb + (size_t)l15 * 64 + quad * 8];   // + kb*64 per tile
    const u16* vbl = vfg + (size_t)bh * 64 * 4096 + lane * 4;  // + (kb>>6)*4096

    for (int kb = 0; kb < 4096; kb += 64) {
        if (max(qb0 + 63 - kb, kb + 63 - qb0) <= W) continue;  // fully masked tile
        bool partial = (kb + 63 >= qb0 - W) && (kb <= qb0 + 63 + W);

        // K fragments direct from global: A of S^T, rows nt*16+l15, d=half*32+quad*8
        const u16* kl = klp + (size_t)kb * 64;
        bf16x8 kf[4][2];
#pragma unroll
        for (int nt = 0; nt < 4; nt++) {
            kf[nt][0] = *(const bf16x8*)(kl + nt * 1024);
            kf[nt][1] = *(const bf16x8*)(kl + nt * 1024 + 32);
        }
        // V fragments (A-frag order, coalesced dwordx2, imm offsets)
        const u16* vl0 = vbl + (size_t)(kb >> 6) * 4096;
        const u16* vl1 = vl0 + 2048;
        s16x4 vfr[16];
#pragma unroll
        for (int f = 0; f < 8; f++) vfr[f]     = *(const s16x4*)(vl0 + f * 256);
#pragma unroll
        for (int f = 0; f < 8; f++) vfr[f + 8] = *(const s16x4*)(vl1 + f * 256);

#pragma unroll
        for (int g = 0; g < 2; g++) {
            f32x4 C[4];
#pragma unroll
            for (int nt = 0; nt < 4; nt++) {
                f32x4 z = (f32x4){0.f, 0.f, 0.f, 0.f};
                C[nt] = mfma16(kf[nt][0], qf[g][0], z);
                C[nt] = mfma16(kf[nt][1], qf[g][1], C[nt]);
            }
            // p = 2^s; masked -> 0; pack into PV B-frags (registers only)
            s16x4 pb[4];
            if (!partial) {
#pragma unroll
                for (int nt = 0; nt < 4; nt++) {
                    float p0 = __builtin_amdgcn_exp2f(C[nt][0]);
                    float p1 = __builtin_amdgcn_exp2f(C[nt][1]);
                    float p2 = __builtin_amdgcn_exp2f(C[nt][2]);
                    float p3 = __builtin_amdgcn_exp2f(C[nt][3]);
                    union { uint2 u; s16x4 v; } pk;
                    pk.u = make_uint2(f2b2(p0, p1), f2b2(p2, p3));
                    pb[nt] = pk.v;
                }
            } else {
                int qr = qb0 + g * 16 + l15;
#pragma unroll
                for (int nt = 0; nt < 4; nt++) {
                    float pv[4];
#pragma unroll
                    for (int r = 0; r < 4; r++) {
                        int key = kb + nt * 16 + quad * 4 + r;
                        int dd = qr - key; dd = dd < 0 ? -dd : dd;
                        pv[r] = (dd <= W) ? 0.f : __builtin_amdgcn_exp2f(C[nt][r]);
                    }
                    union { uint2 u; s16x4 v; } pk;
                    pk.u = make_uint2(f2b2(pv[0], pv[1]), f2b2(pv[2], pv[3]));
                    pb[nt] = pk.v;
                }
            }
            // O^T += V^T * P^T ; row-sum via ones-row MFMA
#pragma unroll
            for (int nt = 0; nt < 4; nt++) {
#pragma unroll
                for (int mb = 0; mb < 4; mb++)
                    O[g][mb] = mfma16k16(vfr[nt * 4 + mb], pb[nt], O[g][mb]);
                O1[g] = mfma16k16(onesA, pb[nt], O1[g]);
            }
        }
    }
    // lsum for qrow=col n sits in O1[g][0] of lanes 0-15 (row 0); broadcast by l15
    int b = bh >> 3, h = bh & 7;
#pragma unroll
    for (int g = 0; g < 2; g++) {
        float ls = __shfl(O1[g][0], l15);
        float inv = 1.0f / ls;
        int qr = qb0 + g * 16 + l15;
        size_t rowoff = ((size_t)(b * 4096 + qr)) * 512 + h * 64;
#pragma unroll
        for (int mb = 0; mb < 4; mb++) {
            uint2 o = make_uint2(f2b2(O[g][mb][0] * inv, O[g][mb][1] * inv),
                                 f2b2(O[g][mb][2] * inv, O[g][mb][3] * inv));
            *(uint2*)&ctx[rowoff + mb * 16 + quad * 4] = o;
        }
    }
}

// ---------------- out GEMM: ctx[8192,512]bf16 x wout[512,512]bf16^T + bias -> fp32 ----
__global__ __launch_bounds__(256) void k_gemm_out(const u16* __restrict__ ab,
                                                  const u16* __restrict__ wb,
                                                  const float* __restrict__ bias,
                                                  float* __restrict__ out) {
    __shared__ u16 As[128][40];
    __shared__ u16 Ws[64][40];
    const int tid = threadIdx.x;
    const int w = tid >> 6, lane = tid & 63, l15 = lane & 15, quad = lane >> 4;
    const int mb = blockIdx.x * 128, nb = blockIdx.y * 64;

    f32x4 acc[2][4];
#pragma unroll
    for (int i = 0; i < 2; i++)
#pragma unroll
        for (int j = 0; j < 4; j++) acc[i][j] = (f32x4){0.f, 0.f, 0.f, 0.f};

    for (int k0 = 0; k0 < 512; k0 += 32) {
        {
            int row = tid >> 1, cc = (tid & 1) * 16;
            const u16* g = &ab[(size_t)(mb + row) * 512 + k0 + cc];
            *(uint4*)&As[row][cc]     = *(const uint4*)g;
            *(uint4*)&As[row][cc + 8] = *(const uint4*)(g + 8);
            int wrow = tid >> 2, wcc = (tid & 3) * 8;
            *(uint4*)&Ws[wrow][wcc] = *(const uint4*)&wb[(size_t)(nb + wrow) * 512 + k0 + wcc];
        }
        __syncthreads();
        bf16x8 a0 = *(const bf16x8*)&As[w * 32 + l15][quad * 8];
        bf16x8 a1 = *(const bf16x8*)&As[w * 32 + 16 + l15][quad * 8];
#pragma unroll
        for (int nt = 0; nt < 4; nt++) {
            bf16x8 bfr = *(const bf16x8*)&Ws[nt * 16 + l15][quad * 8];
            acc[0][nt] = mfma16(a0, bfr, acc[0][nt]);
            acc[1][nt] = mfma16(a1, bfr, acc[1][nt]);
        }
        __syncthreads();
    }
#pragma unroll
    for (int mt = 0; mt < 2; mt++)
#pragma unroll
        for (int nt = 0; nt < 4; nt++) {
            int n = nb + nt * 16 + l15;
            float bs = bias[n];
#pragma unroll
            for (int r = 0; r < 4; r++) {
                int m = mb + w * 32 + mt * 16 + quad * 4 + r;
                out[(size_t)m * 512 + n] = acc[mt][nt][r] + bs;
            }
        }
}

extern "C" void kernel_launch(void* const* d_in, const int* in_sizes, int n_in,
                              void* d_out, int out_size, void* d_ws, size_t ws_size,
                              hipStream_t stream) {
    const float* x    = (const float*)d_in[0];
    const float* wqkv = (const float*)d_in[1];
    const float* bqkv = (const float*)d_in[2];
    const float* wout = (const float*)d_in[3];
    const float* bout = (const float*)d_in[4];
    const int*   win  = (const int*)d_in[5];
    float* out = (float*)d_out;

    u16* xb    = (u16*)d_ws;
    u16* wqkvb = xb    + 8192ull * 512;
    u16* woutb = wqkvb + 1536ull * 512;
    u16* qkvb  = woutb + 512ull * 512;
    u16* ctxb  = qkvb  + 3ull * 16 * 4096 * 64;

    k_cast_all<<<5120, 256, 0, stream>>>(x, wqkv, wout, xb, wqkvb, woutb);
    k_gemm_qkv<<<dim3(64, 12), 256, 0, stream>>>(xb, wqkvb, bqkv, qkvb);
    k_attn<<<dim3(32, 16), 256, 0, stream>>>(qkvb, qkvb + 32ull * 4096 * 64, ctxb, win);
    k_gemm_out<<<dim3(64, 8), 256, 0, stream>>>(ctxb, woutb, bout, out);
}

// Round 7
// 221.580 us; speedup vs baseline: 1.3403x; 1.3403x over previous
//
#include <hip/hip_runtime.h>
#include <hip/hip_bf16.h>

typedef unsigned short u16;
typedef __bf16 bf16x8 __attribute__((ext_vector_type(8)));
typedef short s16x4 __attribute__((ext_vector_type(4)));
typedef float f32x4 __attribute__((ext_vector_type(4)));

__device__ __forceinline__ f32x4 mfma16(bf16x8 a, bf16x8 b, f32x4 c) {
    return __builtin_amdgcn_mfma_f32_16x16x32_bf16(a, b, c, 0, 0, 0);
}
__device__ __forceinline__ f32x4 mfma16k16(s16x4 a, s16x4 b, f32x4 c) {
    return __builtin_amdgcn_mfma_f32_16x16x16bf16_1k(a, b, c, 0, 0, 0);
}

// fp32 -> bf16 bits, round-to-nearest-even
__device__ __forceinline__ u16 f2b(float x) {
    union { float f; unsigned u; } a; a.f = x;
    unsigned r = a.u + 0x7fffu + ((a.u >> 16) & 1u);
    return (u16)(r >> 16);
}
// packed pair (RTNE, identical result to f2b per element)
__device__ __forceinline__ unsigned f2b2(float a, float b) {
    union { __hip_bfloat162 h; unsigned u; } cv;
    cv.h = __float22bfloat162_rn(make_float2(a, b));
    return cv.u;
}
// async 16B global -> LDS (DMA, vmcnt-tracked); dest = wave-uniform base + lane*16
__device__ __forceinline__ void async16(const u16* g, u16* l) {
    __builtin_amdgcn_global_load_lds((const __attribute__((address_space(1))) unsigned int*)g,
                                     (__attribute__((address_space(3))) unsigned int*)l, 16, 0, 0);
}

// ---------------- fused cast fp32 -> bf16 for all three inputs ----------------
#define NX  (8192 * 512)
#define NWQ (1536 * 512)
#define NWO (512 * 512)
__global__ __launch_bounds__(256) void k_cast_all(const float* __restrict__ x,
                                                  const float* __restrict__ wq,
                                                  const float* __restrict__ wo,
                                                  u16* __restrict__ xb,
                                                  u16* __restrict__ wqb,
                                                  u16* __restrict__ wob) {
    int i = (blockIdx.x * 256 + threadIdx.x) * 4;
    const float* s; u16* d; int off;
    if (i < NX)            { s = x;  d = xb;  off = i; }
    else if (i < NX + NWQ) { s = wq; d = wqb; off = i - NX; }
    else                   { s = wo; d = wob; off = i - NX - NWQ; }
    float4 f = *(const float4*)&s[off];
    uint2 o = make_uint2(f2b2(f.x, f.y), f2b2(f.z, f.w));
    *(uint2*)&d[off] = o;
}

// ---------------- QKV GEMM: [8192,512]bf16 x [1536,512]bf16^T ----------------
// q -> [B*H][S][64] row-major (pre-scaled 0.125/ln2)
// k -> KF[bh][kt][nt][h][quad][l15][8]   (QK^T A-fragment order)
// v -> VF[bh][kt][f=nt*4+mb][quad][l15][4] (PV A-fragment order)
__global__ __launch_bounds__(256) void k_gemm_qkv(const u16* __restrict__ xb,
                                                  const u16* __restrict__ wb,
                                                  const float* __restrict__ bias,
                                                  u16* __restrict__ qkvout) {
    __shared__ u16 As[128][40];
    __shared__ u16 Ws[128][40];
    const int tid = threadIdx.x;
    const int w = tid >> 6, lane = tid & 63, l15 = lane & 15, quad = lane >> 4;
    const int mb = blockIdx.x * 128, nb = blockIdx.y * 128;

    f32x4 acc[2][8];
#pragma unroll
    for (int i = 0; i < 2; i++)
#pragma unroll
        for (int j = 0; j < 8; j++) acc[i][j] = (f32x4){0.f, 0.f, 0.f, 0.f};

    for (int k0 = 0; k0 < 512; k0 += 32) {
        {
            int row = tid >> 1, cc = (tid & 1) * 16;
            const u16* g = &xb[(size_t)(mb + row) * 512 + k0 + cc];
            *(uint4*)&As[row][cc]     = *(const uint4*)g;
            *(uint4*)&As[row][cc + 8] = *(const uint4*)(g + 8);
            const u16* gw = &wb[(size_t)(nb + row) * 512 + k0 + cc];
            *(uint4*)&Ws[row][cc]     = *(const uint4*)gw;
            *(uint4*)&Ws[row][cc + 8] = *(const uint4*)(gw + 8);
        }
        __syncthreads();
        bf16x8 a0 = *(const bf16x8*)&As[w * 32 + l15][quad * 8];
        bf16x8 a1 = *(const bf16x8*)&As[w * 32 + 16 + l15][quad * 8];
#pragma unroll
        for (int nt = 0; nt < 8; nt++) {
            bf16x8 bfr = *(const bf16x8*)&Ws[nt * 16 + l15][quad * 8];
            acc[0][nt] = mfma16(a0, bfr, acc[0][nt]);
            acc[1][nt] = mfma16(a1, bfr, acc[1][nt]);
        }
        __syncthreads();
    }
    const int seg = nb >> 9;          // 0=q 1=k 2=v (128-tile stays in one seg)
    u16* obase = qkvout + (size_t)seg * (16ull * 4096 * 64);
    if (seg == 0) {
        const float sc = 0.125f * 1.44269504088896340736f;
#pragma unroll
        for (int mt = 0; mt < 2; mt++)
#pragma unroll
            for (int nt = 0; nt < 8; nt++) {
                int dcol = nb + nt * 16 + l15;
                int hh = (dcol >> 6) & 7, dloc = dcol & 63;
                float bs = bias[dcol];
#pragma unroll
                for (int r = 0; r < 4; r++) {
                    int m = mb + w * 32 + mt * 16 + quad * 4 + r;
                    float vv = (acc[mt][nt][r] + bs) * sc;
                    int b = m >> 12, s = m & 4095;
                    obase[((size_t)((b * 8 + hh) * 4096 + s)) * 64 + dloc] = f2b(vv);
                }
            }
    } else if (seg == 1) {
        // K in QK^T-A-frag order: tile idx = (((nt*2+h)*4+quad)*16+l15)*8 + j
#pragma unroll
        for (int mt = 0; mt < 2; mt++)
#pragma unroll
            for (int nt = 0; nt < 8; nt++) {
                int dcol = nb + nt * 16 + l15;
                int hh = (dcol >> 6) & 7, d = dcol & 63;
                int h2 = d >> 5, qk = (d & 31) >> 3, j = d & 7;
                float bs = bias[dcol];
                int m0 = mb + w * 32 + mt * 16 + quad * 4;
                int b = m0 >> 12, s0 = m0 & 4095;
                int kt = s0 >> 6, knt = (s0 & 63) >> 4, kl0 = s0 & 15;
                size_t base = (((((size_t)(b * 8 + hh) * 64 + kt) * 4 + knt) * 2 + h2) * 4 + qk) * 16;
#pragma unroll
                for (int r = 0; r < 4; r++)
                    obase[(base + kl0 + r) * 8 + j] = f2b(acc[mt][nt][r] + bs);
            }
    } else {
        // V in PV-A-frag order
#pragma unroll
        for (int mt = 0; mt < 2; mt++)
#pragma unroll
            for (int nt = 0; nt < 8; nt++) {
                int c = nb + nt * 16 + l15;
                int hh = (c >> 6) & 7, d = c & 63;
                int mbv = d >> 4, l15v = d & 15;
                float bs = bias[c];
                int m0 = mb + w * 32 + mt * 16 + quad * 4;
                int b = m0 >> 12, si = m0 & 4095;
                int kt = si >> 6, ka = si & 63;
                int ntv = ka >> 4;
                uint2 o = make_uint2(f2b2(acc[mt][nt][0] + bs, acc[mt][nt][1] + bs),
                                     f2b2(acc[mt][nt][2] + bs, acc[mt][nt][3] + bs));
                size_t F4 = ((((((size_t)(b * 8 + hh) * 64 + kt) * 4 + ntv) * 4 + mbv) * 4 + quad) * 16 + l15v);
                *(uint2*)&obase[F4 * 4] = o;
            }
    }
}

// ---------------- flash attention v7 (inverted-window mask) -----------------
// 256 thr = 4 waves x 32 q-rows (128-row block). K,V pre-scattered to MFMA
// fragment order in global; staged 8KB/tile each via async global_load_lds
// into double-buffered LDS (single barrier/iter, prefetch issued a full
// compute-phase ahead). P in registers; lsum via ones-row MFMA.
__global__ __launch_bounds__(256, 2) void k_attn(const u16* __restrict__ qg,
                                                 const u16* __restrict__ kfg,
                                                 const u16* __restrict__ vfg,
                                                 u16* __restrict__ ctx,
                                                 const int* __restrict__ win) {
    __shared__ u16 KL[2][4096];
    __shared__ u16 VL[2][4096];
    const int tid = threadIdx.x;
    const int w = tid >> 6, lane = tid & 63, l15 = lane & 15, quad = lane >> 4;
    const int bh = blockIdx.y;
    const int qb0 = blockIdx.x * 128;          // block's 128 q-rows
    const int qb0w = qb0 + w * 32;             // this wave's 32
    const int W = win[0];
    const size_t bhb = (size_t)bh * 4096 * 64;

    // Q fragments: B-operand of S^T = K*Q^T
    bf16x8 qf[2][2];
#pragma unroll
    for (int g = 0; g < 2; g++) {
        const u16* qrow = &qg[bhb + (size_t)(qb0w + g * 16 + l15) * 64];
        qf[g][0] = *(const bf16x8*)&qrow[quad * 8];
        qf[g][1] = *(const bf16x8*)&qrow[32 + quad * 8];
    }
    // ones A-frag (row 0 = 1.0) for lsum-in-MFMA
    s16x4 onesA;
    {
        short v = (l15 == 0) ? (short)0x3F80 : (short)0;
        onesA[0] = v; onesA[1] = v; onesA[2] = v; onesA[3] = v;
    }

    f32x4 O[2][4];
#pragma unroll
    for (int g = 0; g < 2; g++)
#pragma unroll
        for (int mb = 0; mb < 4; mb++) O[g][mb] = (f32x4){0.f, 0.f, 0.f, 0.f};
    f32x4 O1[2] = {(f32x4){0.f, 0.f, 0.f, 0.f}, (f32x4){0.f, 0.f, 0.f, 0.f}};

    const u16* kbase = kfg + bhb;   // [kt][4096]
    const u16* vbase = vfg + bhb;
    const int soff = w * 1024 + lane * 8;      // this wave's DMA slice (u16)

    // tile iteration with skip of fully-masked tiles (uniform)
    auto skip = [&](int kb) {
        return max(qb0 + 127 - kb, kb + 63 - qb0) <= W;
    };
    int kb = 0;
    while (kb < 4096 && skip(kb)) kb += 64;
    // prologue: stage first tile into buffer 0
    {
        const u16* kt_p = kbase + (size_t)(kb >> 6) * 4096;
        const u16* vt_p = vbase + (size_t)(kb >> 6) * 4096;
        async16(kt_p + soff, &KL[0][soff]);
        async16(kt_p + soff + 512, &KL[0][soff + 512]);
        async16(vt_p + soff, &VL[0][soff]);
        async16(vt_p + soff + 512, &VL[0][soff + 512]);
    }
    __syncthreads();
    int p = 0;
    while (kb < 4096) {
        int kb_next = kb + 64;
        while (kb_next < 4096 && skip(kb_next)) kb_next += 64;
        if (kb_next < 4096) {   // prefetch next tile into alternate buffer
            const u16* kt_p = kbase + (size_t)(kb_next >> 6) * 4096;
            const u16* vt_p = vbase + (size_t)(kb_next >> 6) * 4096;
            async16(kt_p + soff, &KL[p ^ 1][soff]);
            async16(kt_p + soff + 512, &KL[p ^ 1][soff + 512]);
            async16(vt_p + soff, &VL[p ^ 1][soff]);
            async16(vt_p + soff + 512, &VL[p ^ 1][soff + 512]);
        }
        bool partial = (kb + 63 >= qb0 - W) && (kb <= qb0 + 127 + W);
        // K frags: A of S^T  [nt][h][quad][l15][8]
        bf16x8 kf[4][2];
#pragma unroll
        for (int nt = 0; nt < 4; nt++) {
            kf[nt][0] = *(const bf16x8*)&KL[p][(((nt * 2 + 0) * 4 + quad) * 16 + l15) * 8];
            kf[nt][1] = *(const bf16x8*)&KL[p][(((nt * 2 + 1) * 4 + quad) * 16 + l15) * 8];
        }
        // V frags: A of PV  [f][quad][l15][4]
        s16x4 vfr[16];
#pragma unroll
        for (int f = 0; f < 16; f++)
            vfr[f] = *(const s16x4*)&VL[p][((f * 4 + quad) * 16 + l15) * 4];

#pragma unroll
        for (int g = 0; g < 2; g++) {
            f32x4 C[4];
#pragma unroll
            for (int nt = 0; nt < 4; nt++) {
                f32x4 z = (f32x4){0.f, 0.f, 0.f, 0.f};
                C[nt] = mfma16(kf[nt][0], qf[g][0], z);
                C[nt] = mfma16(kf[nt][1], qf[g][1], C[nt]);
            }
            s16x4 pb[4];
            if (!partial) {
#pragma unroll
                for (int nt = 0; nt < 4; nt++) {
                    float p0 = __builtin_amdgcn_exp2f(C[nt][0]);
                    float p1 = __builtin_amdgcn_exp2f(C[nt][1]);
                    float p2 = __builtin_amdgcn_exp2f(C[nt][2]);
                    float p3 = __builtin_amdgcn_exp2f(C[nt][3]);
                    union { uint2 u; s16x4 v; } pk;
                    pk.u = make_uint2(f2b2(p0, p1), f2b2(p2, p3));
                    pb[nt] = pk.v;
                }
            } else {
                int qr = qb0w + g * 16 + l15;
#pragma unroll
                for (int nt = 0; nt < 4; nt++) {
                    float pv[4];
#pragma unroll
                    for (int r = 0; r < 4; r++) {
                        int key = kb + nt * 16 + quad * 4 + r;
                        int dd = qr - key; dd = dd < 0 ? -dd : dd;
                        pv[r] = (dd <= W) ? 0.f : __builtin_amdgcn_exp2f(C[nt][r]);
                    }
                    union { uint2 u; s16x4 v; } pk;
                    pk.u = make_uint2(f2b2(pv[0], pv[1]), f2b2(pv[2], pv[3]));
                    pb[nt] = pk.v;
                }
            }
#pragma unroll
            for (int nt = 0; nt < 4; nt++) {
#pragma unroll
                for (int mb = 0; mb < 4; mb++)
                    O[g][mb] = mfma16k16(vfr[nt * 4 + mb], pb[nt], O[g][mb]);
                O1[g] = mfma16k16(onesA, pb[nt], O1[g]);
            }
        }
        if (kb_next < 4096) {
            __syncthreads();   // drains prefetch DMA (already landed) + buffer handoff
            p ^= 1;
        }
        kb = kb_next;
    }
    // lsum sits in O1[g][0] of lanes 0-15 (C row 0); broadcast by l15
    int b = bh >> 3, h = bh & 7;
#pragma unroll
    for (int g = 0; g < 2; g++) {
        float ls = __shfl(O1[g][0], l15);
        float inv = 1.0f / ls;
        int qr = qb0w + g * 16 + l15;
        size_t rowoff = ((size_t)(b * 4096 + qr)) * 512 + h * 64;
#pragma unroll
        for (int mb = 0; mb < 4; mb++) {
            uint2 o = make_uint2(f2b2(O[g][mb][0] * inv, O[g][mb][1] * inv),
                                 f2b2(O[g][mb][2] * inv, O[g][mb][3] * inv));
            *(uint2*)&ctx[rowoff + mb * 16 + quad * 4] = o;
        }
    }
}

// ---------------- out GEMM: ctx[8192,512]bf16 x wout[512,512]bf16^T + bias -> fp32 ----
__global__ __launch_bounds__(256) void k_gemm_out(const u16* __restrict__ ab,
                                                  const u16* __restrict__ wb,
                                                  const float* __restrict__ bias,
                                                  float* __restrict__ out) {
    __shared__ u16 As[128][40];
    __shared__ u16 Ws[64][40];
    const int tid = threadIdx.x;
    const int w = tid >> 6, lane = tid & 63, l15 = lane & 15, quad = lane >> 4;
    const int mb = blockIdx.x * 128, nb = blockIdx.y * 64;

    f32x4 acc[2][4];
#pragma unroll
    for (int i = 0; i < 2; i++)
#pragma unroll
        for (int j = 0; j < 4; j++) acc[i][j] = (f32x4){0.f, 0.f, 0.f, 0.f};

    for (int k0 = 0; k0 < 512; k0 += 32) {
        {
            int row = tid >> 1, cc = (tid & 1) * 16;
            const u16* g = &ab[(size_t)(mb + row) * 512 + k0 + cc];
            *(uint4*)&As[row][cc]     = *(const uint4*)g;
            *(uint4*)&As[row][cc + 8] = *(const uint4*)(g + 8);
            int wrow = tid >> 2, wcc = (tid & 3) * 8;
            *(uint4*)&Ws[wrow][wcc] = *(const uint4*)&wb[(size_t)(nb + wrow) * 512 + k0 + wcc];
        }
        __syncthreads();
        bf16x8 a0 = *(const bf16x8*)&As[w * 32 + l15][quad * 8];
        bf16x8 a1 = *(const bf16x8*)&As[w * 32 + 16 + l15][quad * 8];
#pragma unroll
        for (int nt = 0; nt < 4; nt++) {
            bf16x8 bfr = *(const bf16x8*)&Ws[nt * 16 + l15][quad * 8];
            acc[0][nt] = mfma16(a0, bfr, acc[0][nt]);
            acc[1][nt] = mfma16(a1, bfr, acc[1][nt]);
        }
        __syncthreads();
    }
#pragma unroll
    for (int mt = 0; mt < 2; mt++)
#pragma unroll
        for (int nt = 0; nt < 4; nt++) {
            int n = nb + nt * 16 + l15;
            float bs = bias[n];
#pragma unroll
            for (int r = 0; r < 4; r++) {
                int m = mb + w * 32 + mt * 16 + quad * 4 + r;
                out[(size_t)m * 512 + n] = acc[mt][nt][r] + bs;
            }
        }
}

extern "C" void kernel_launch(void* const* d_in, const int* in_sizes, int n_in,
                              void* d_out, int out_size, void* d_ws, size_t ws_size,
                              hipStream_t stream) {
    const float* x    = (const float*)d_in[0];
    const float* wqkv = (const float*)d_in[1];
    const float* bqkv = (const float*)d_in[2];
    const float* wout = (const float*)d_in[3];
    const float* bout = (const float*)d_in[4];
    const int*   win  = (const int*)d_in[5];
    float* out = (float*)d_out;

    u16* xb    = (u16*)d_ws;
    u16* wqkvb = xb    + 8192ull * 512;
    u16* woutb = wqkvb + 1536ull * 512;
    u16* qkvb  = woutb + 512ull * 512;
    u16* ctxb  = qkvb  + 3ull * 16 * 4096 * 64;

    k_cast_all<<<5120, 256, 0, stream>>>(x, wqkv, wout, xb, wqkvb, woutb);
    k_gemm_qkv<<<dim3(64, 12), 256, 0, stream>>>(xb, wqkvb, bqkv, qkvb);
    k_attn<<<dim3(32, 16), 256, 0, stream>>>(qkvb, qkvb + 16ull * 4096 * 64,
                                             qkvb + 32ull * 4096 * 64, ctxb, win);
    k_gemm_out<<<dim3(64, 8), 256, 0, stream>>>(ctxb, woutb, bout, out);
}

// Round 8
// 213.599 us; speedup vs baseline: 1.3904x; 1.0374x over previous
//
#include <hip/hip_runtime.h>
#include <hip/hip_bf16.h>

typedef unsigned short u16;
typedef __bf16 bf16x8 __attribute__((ext_vector_type(8)));
typedef short s16x4 __attribute__((ext_vector_type(4)));
typedef float f32x4 __attribute__((ext_vector_type(4)));

__device__ __forceinline__ f32x4 mfma16(bf16x8 a, bf16x8 b, f32x4 c) {
    return __builtin_amdgcn_mfma_f32_16x16x32_bf16(a, b, c, 0, 0, 0);
}
__device__ __forceinline__ f32x4 mfma16k16(s16x4 a, s16x4 b, f32x4 c) {
    return __builtin_amdgcn_mfma_f32_16x16x16bf16_1k(a, b, c, 0, 0, 0);
}

// fp32 -> bf16 bits, round-to-nearest-even
__device__ __forceinline__ u16 f2b(float x) {
    union { float f; unsigned u; } a; a.f = x;
    unsigned r = a.u + 0x7fffu + ((a.u >> 16) & 1u);
    return (u16)(r >> 16);
}
__device__ __forceinline__ unsigned f2b2(float a, float b) {
    union { __hip_bfloat162 h; unsigned u; } cv;
    cv.h = __float22bfloat162_rn(make_float2(a, b));
    return cv.u;
}
// async 16B global -> LDS (DMA, vmcnt-tracked)
__device__ __forceinline__ void async16(const u16* g, u16* l) {
    __builtin_amdgcn_global_load_lds((const __attribute__((address_space(1))) unsigned int*)g,
                                     (__attribute__((address_space(3))) unsigned int*)l, 16, 0, 0);
}

// ---------------- fused cast fp32 -> bf16 for all three inputs ----------------
#define NX  (8192 * 512)
#define NWQ (1536 * 512)
#define NWO (512 * 512)
__global__ __launch_bounds__(256) void k_cast_all(const float* __restrict__ x,
                                                  const float* __restrict__ wq,
                                                  const float* __restrict__ wo,
                                                  u16* __restrict__ xb,
                                                  u16* __restrict__ wqb,
                                                  u16* __restrict__ wob) {
    int i = (blockIdx.x * 256 + threadIdx.x) * 4;
    const float* s; u16* d; int off;
    if (i < NX)            { s = x;  d = xb;  off = i; }
    else if (i < NX + NWQ) { s = wq; d = wqb; off = i - NX; }
    else                   { s = wo; d = wob; off = i - NX - NWQ; }
    float4 f = *(const float4*)&s[off];
    uint2 o = make_uint2(f2b2(f.x, f.y), f2b2(f.z, f.w));
    *(uint2*)&d[off] = o;
}

// ---------------- QKV GEMM (async-DMA double-buffered, m97 pattern) ----------
// q,k -> [B*H][S][64] bf16 (q pre-scaled 0.125/ln2)
// v   -> VF[bh][kt][f][quad][l15][4]  (PV A-fragment order)
__global__ __launch_bounds__(256, 3) void k_gemm_qkv(const u16* __restrict__ xb,
                                                     const u16* __restrict__ wb,
                                                     const float* __restrict__ bias,
                                                     u16* __restrict__ qkvout) {
    __shared__ u16 AL[2][4096];   // 128 rows x 32 (k-slice), unpadded for DMA
    __shared__ u16 WL[2][4096];
    const int tid = threadIdx.x;
    const int w = tid >> 6, lane = tid & 63, l15 = lane & 15, quad = lane >> 4;
    const int mb = blockIdx.x * 128, nb = blockIdx.y * 128;

    f32x4 acc[2][8];
#pragma unroll
    for (int i = 0; i < 2; i++)
#pragma unroll
        for (int j = 0; j < 8; j++) acc[i][j] = (f32x4){0.f, 0.f, 0.f, 0.f};

    // DMA setup: inst t covers rows (w*32 + t*16 + lane>>2), col chunk (lane&3)*8
    const u16* agp = xb + (size_t)(mb + w * 32 + (lane >> 2)) * 512 + (lane & 3) * 8;
    const u16* wgp = wb + (size_t)(nb + w * 32 + (lane >> 2)) * 512 + (lane & 3) * 8;
    const int ldst = w * 1024 + lane * 8;

    async16(agp, &AL[0][ldst]);
    async16(agp + 16 * 512, &AL[0][ldst + 512]);
    async16(wgp, &WL[0][ldst]);
    async16(wgp + 16 * 512, &WL[0][ldst + 512]);
    __syncthreads();
    int p = 0;
    for (int ks = 0; ks < 16; ks++) {
        if (ks < 15) {
            int k0n = (ks + 1) * 32;
            async16(agp + k0n, &AL[p ^ 1][ldst]);
            async16(agp + 16 * 512 + k0n, &AL[p ^ 1][ldst + 512]);
            async16(wgp + k0n, &WL[p ^ 1][ldst]);
            async16(wgp + 16 * 512 + k0n, &WL[p ^ 1][ldst + 512]);
        }
        bf16x8 a0 = *(const bf16x8*)&AL[p][(w * 32 + l15) * 32 + quad * 8];
        bf16x8 a1 = *(const bf16x8*)&AL[p][(w * 32 + 16 + l15) * 32 + quad * 8];
#pragma unroll
        for (int nt = 0; nt < 8; nt++) {
            bf16x8 bfr = *(const bf16x8*)&WL[p][(nt * 16 + l15) * 32 + quad * 8];
            acc[0][nt] = mfma16(a0, bfr, acc[0][nt]);
            acc[1][nt] = mfma16(a1, bfr, acc[1][nt]);
        }
        if (ks < 15) { __syncthreads(); p ^= 1; }
    }
    const int seg = nb >> 9;          // 0=q 1=k 2=v
    u16* obase = qkvout + (size_t)seg * (16ull * 4096 * 64);
    if (seg < 2) {
        const float sc = (seg == 0) ? 0.125f * 1.44269504088896340736f : 1.0f;
#pragma unroll
        for (int mt = 0; mt < 2; mt++)
#pragma unroll
            for (int nt = 0; nt < 8; nt++) {
                int dcol = nb + nt * 16 + l15;
                int hh = (dcol >> 6) & 7, dloc = dcol & 63;
                float bs = bias[dcol];
#pragma unroll
                for (int r = 0; r < 4; r++) {
                    int m = mb + w * 32 + mt * 16 + quad * 4 + r;
                    float vv = (acc[mt][nt][r] + bs) * sc;
                    int b = m >> 12, s = m & 4095;
                    obase[((size_t)((b * 8 + hh) * 4096 + s)) * 64 + dloc] = f2b(vv);
                }
            }
    } else {
        // V in PV-A-frag order
#pragma unroll
        for (int mt = 0; mt < 2; mt++)
#pragma unroll
            for (int nt = 0; nt < 8; nt++) {
                int c = nb + nt * 16 + l15;
                int hh = (c >> 6) & 7, d = c & 63;
                int mbv = d >> 4, l15v = d & 15;
                float bs = bias[c];
                int m0 = mb + w * 32 + mt * 16 + quad * 4;
                int b = m0 >> 12, si = m0 & 4095;
                int kt = si >> 6, ka = si & 63;
                int ntv = ka >> 4;
                uint2 o = make_uint2(f2b2(acc[mt][nt][0] + bs, acc[mt][nt][1] + bs),
                                     f2b2(acc[mt][nt][2] + bs, acc[mt][nt][3] + bs));
                size_t F4 = ((((((size_t)(b * 8 + hh) * 64 + kt) * 4 + ntv) * 4 + mbv) * 4 + quad) * 16 + l15v);
                *(uint2*)&obase[F4 * 4] = o;
            }
    }
}

// ---------------- flash attention v8 (inverted-window mask) -----------------
// 128 thr = 2 waves x 32 q-rows, grid (64,16) -> 4 blocks/CU (fine-grain
// barrier domains). K row-major in global, DMA-staged with XOR-swizzled
// SOURCE addresses (bank-conflict-free reads, memcpy-contiguous dest).
// V fragment-ordered in global. Tile-level partial branch; QK/exp/PV batched.
__global__ __launch_bounds__(128, 2) void k_attn(const u16* __restrict__ qg,
                                                 const u16* __restrict__ kg,
                                                 const u16* __restrict__ vfg,
                                                 u16* __restrict__ ctx,
                                                 const int* __restrict__ win) {
    __shared__ u16 KL[2][4096];   // [row][chunk^(row&7)][8]
    __shared__ u16 VL[2][4096];   // frag order
    const int tid = threadIdx.x;
    const int w = tid >> 6, lane = tid & 63, l15 = lane & 15, quad = lane >> 4;
    const int bh = blockIdx.y;
    const int qb0 = blockIdx.x * 64;
    const int qb0w = qb0 + w * 32;
    const int W = win[0];
    const size_t bhb = (size_t)bh * 4096 * 64;

    bf16x8 qf[2][2];
#pragma unroll
    for (int g = 0; g < 2; g++) {
        const u16* qrow = &qg[bhb + (size_t)(qb0w + g * 16 + l15) * 64];
        qf[g][0] = *(const bf16x8*)&qrow[quad * 8];
        qf[g][1] = *(const bf16x8*)&qrow[32 + quad * 8];
    }
    s16x4 onesA;
    {
        short v = (l15 == 0) ? (short)0x3F80 : (short)0;
        onesA[0] = v; onesA[1] = v; onesA[2] = v; onesA[3] = v;
    }

    f32x4 O[2][4];
#pragma unroll
    for (int g = 0; g < 2; g++)
#pragma unroll
        for (int mb = 0; mb < 4; mb++) O[g][mb] = (f32x4){0.f, 0.f, 0.f, 0.f};
    f32x4 O1[2] = {(f32x4){0.f, 0.f, 0.f, 0.f}, (f32x4){0.f, 0.f, 0.f, 0.f}};

    // DMA addressing: inst t covers K rows w*32+t*8+(lane>>3); src chunk
    // (lane&7)^(lane>>3) implements LDS[row][c^(row&7)] = K[row][c]
    const u16* kgp = kg + bhb + (size_t)(w * 32 + (lane >> 3)) * 64
                     + (((lane & 7) ^ (lane >> 3)) * 8);
    const u16* vgp = vfg + bhb + (size_t)(w * 2048 + lane * 8);
    const int ldst = w * 2048 + lane * 8;

    auto skip = [&](int kb) { return max(qb0 + 63 - kb, kb + 63 - qb0) <= W; };
    int kb = 0;
    while (kb < 4096 && skip(kb)) kb += 64;
    {
        const u16* kt_p = kgp + (size_t)kb * 64;
        const u16* vt_p = vgp + (size_t)(kb >> 6) * 4096;
#pragma unroll
        for (int t = 0; t < 4; t++) async16(kt_p + t * 512, &KL[0][ldst + t * 512]);
#pragma unroll
        for (int t = 0; t < 4; t++) async16(vt_p + t * 512, &VL[0][ldst + t * 512]);
    }
    __syncthreads();
    int p = 0;
    while (kb < 4096) {
        int kb_next = kb + 64;
        while (kb_next < 4096 && skip(kb_next)) kb_next += 64;
        if (kb_next < 4096) {
            const u16* kt_p = kgp + (size_t)kb_next * 64;
            const u16* vt_p = vgp + (size_t)(kb_next >> 6) * 4096;
#pragma unroll
            for (int t = 0; t < 4; t++) async16(kt_p + t * 512, &KL[p ^ 1][ldst + t * 512]);
#pragma unroll
            for (int t = 0; t < 4; t++) async16(vt_p + t * 512, &VL[p ^ 1][ldst + t * 512]);
        }
        const bool partial = (kb + 63 >= qb0 - W) && (kb <= qb0 + 63 + W);
        // K frags (swizzle-corrected), V frags
        bf16x8 kf[4][2];
        const int rs = l15 & 7;
#pragma unroll
        for (int nt = 0; nt < 4; nt++) {
            kf[nt][0] = *(const bf16x8*)&KL[p][(nt * 16 + l15) * 64 + ((quad ^ rs) * 8)];
            kf[nt][1] = *(const bf16x8*)&KL[p][(nt * 16 + l15) * 64 + (((quad + 4) ^ rs) * 8)];
        }
        s16x4 vfr[16];
#pragma unroll
        for (int f = 0; f < 16; f++)
            vfr[f] = *(const s16x4*)&VL[p][((f * 4 + quad) * 16 + l15) * 4];

        // QK both groups (16 independent MFMAs)
        f32x4 C[2][4];
#pragma unroll
        for (int g = 0; g < 2; g++)
#pragma unroll
            for (int nt = 0; nt < 4; nt++) {
                f32x4 z = (f32x4){0.f, 0.f, 0.f, 0.f};
                C[g][nt] = mfma16(kf[nt][0], qf[g][0], z);
                C[g][nt] = mfma16(kf[nt][1], qf[g][1], C[g][nt]);
            }
        // exp + pack (both groups batched)
        s16x4 pb[2][4];
        if (!partial) {
#pragma unroll
            for (int g = 0; g < 2; g++)
#pragma unroll
                for (int nt = 0; nt < 4; nt++) {
                    float p0 = __builtin_amdgcn_exp2f(C[g][nt][0]);
                    float p1 = __builtin_amdgcn_exp2f(C[g][nt][1]);
                    float p2 = __builtin_amdgcn_exp2f(C[g][nt][2]);
                    float p3 = __builtin_amdgcn_exp2f(C[g][nt][3]);
                    union { uint2 u; s16x4 v; } pk;
                    pk.u = make_uint2(f2b2(p0, p1), f2b2(p2, p3));
                    pb[g][nt] = pk.v;
                }
        } else {
#pragma unroll
            for (int g = 0; g < 2; g++) {
                int qr = qb0w + g * 16 + l15;
#pragma unroll
                for (int nt = 0; nt < 4; nt++) {
                    float pv[4];
#pragma unroll
                    for (int r = 0; r < 4; r++) {
                        int key = kb + nt * 16 + quad * 4 + r;
                        int dd = qr - key; dd = dd < 0 ? -dd : dd;
                        pv[r] = (dd <= W) ? 0.f : __builtin_amdgcn_exp2f(C[g][nt][r]);
                    }
                    union { uint2 u; s16x4 v; } pk;
                    pk.u = make_uint2(f2b2(pv[0], pv[1]), f2b2(pv[2], pv[3]));
                    pb[g][nt] = pk.v;
                }
            }
        }
        // PV + ones (both groups batched)
#pragma unroll
        for (int nt = 0; nt < 4; nt++)
#pragma unroll
            for (int g = 0; g < 2; g++) {
#pragma unroll
                for (int mb = 0; mb < 4; mb++)
                    O[g][mb] = mfma16k16(vfr[nt * 4 + mb], pb[g][nt], O[g][mb]);
                O1[g] = mfma16k16(onesA, pb[g][nt], O1[g]);
            }
        if (kb_next < 4096) { __syncthreads(); p ^= 1; }
        kb = kb_next;
    }
    int b = bh >> 3, h = bh & 7;
#pragma unroll
    for (int g = 0; g < 2; g++) {
        float ls = __shfl(O1[g][0], l15);
        float inv = 1.0f / ls;
        int qr = qb0w + g * 16 + l15;
        size_t rowoff = ((size_t)(b * 4096 + qr)) * 512 + h * 64;
#pragma unroll
        for (int mb = 0; mb < 4; mb++) {
            uint2 o = make_uint2(f2b2(O[g][mb][0] * inv, O[g][mb][1] * inv),
                                 f2b2(O[g][mb][2] * inv, O[g][mb][3] * inv));
            *(uint2*)&ctx[rowoff + mb * 16 + quad * 4] = o;
        }
    }
}

// ---------------- out GEMM (async-DMA double-buffered) -----------------------
__global__ __launch_bounds__(256, 2) void k_gemm_out(const u16* __restrict__ ab,
                                                     const u16* __restrict__ wb,
                                                     const float* __restrict__ bias,
                                                     float* __restrict__ out) {
    __shared__ u16 AL[2][4096];
    __shared__ u16 WL[2][2048];   // 64 rows x 32
    const int tid = threadIdx.x;
    const int w = tid >> 6, lane = tid & 63, l15 = lane & 15, quad = lane >> 4;
    const int mb = blockIdx.x * 128, nb = blockIdx.y * 64;

    f32x4 acc[2][4];
#pragma unroll
    for (int i = 0; i < 2; i++)
#pragma unroll
        for (int j = 0; j < 4; j++) acc[i][j] = (f32x4){0.f, 0.f, 0.f, 0.f};

    const u16* agp = ab + (size_t)(mb + w * 32 + (lane >> 2)) * 512 + (lane & 3) * 8;
    const u16* wgp = wb + (size_t)(nb + w * 16 + (lane >> 2)) * 512 + (lane & 3) * 8;
    const int ldstA = w * 1024 + lane * 8;
    const int ldstW = w * 512 + lane * 8;

    async16(agp, &AL[0][ldstA]);
    async16(agp + 16 * 512, &AL[0][ldstA + 512]);
    async16(wgp, &WL[0][ldstW]);
    __syncthreads();
    int p = 0;
    for (int ks = 0; ks < 16; ks++) {
        if (ks < 15) {
            int k0n = (ks + 1) * 32;
            async16(agp + k0n, &AL[p ^ 1][ldstA]);
            async16(agp + 16 * 512 + k0n, &AL[p ^ 1][ldstA + 512]);
            async16(wgp + k0n, &WL[p ^ 1][ldstW]);
        }
        bf16x8 a0 = *(const bf16x8*)&AL[p][(w * 32 + l15) * 32 + quad * 8];
        bf16x8 a1 = *(const bf16x8*)&AL[p][(w * 32 + 16 + l15) * 32 + quad * 8];
#pragma unroll
        for (int nt = 0; nt < 4; nt++) {
            bf16x8 bfr = *(const bf16x8*)&WL[p][(nt * 16 + l15) * 32 + quad * 8];
            acc[0][nt] = mfma16(a0, bfr, acc[0][nt]);
            acc[1][nt] = mfma16(a1, bfr, acc[1][nt]);
        }
        if (ks < 15) { __syncthreads(); p ^= 1; }
    }
#pragma unroll
    for (int mt = 0; mt < 2; mt++)
#pragma unroll
        for (int nt = 0; nt < 4; nt++) {
            int n = nb + nt * 16 + l15;
            float bs = bias[n];
#pragma unroll
            for (int r = 0; r < 4; r++) {
                int m = mb + w * 32 + mt * 16 + quad * 4 + r;
                out[(size_t)m * 512 + n] = acc[mt][nt][r] + bs;
            }
        }
}

extern "C" void kernel_launch(void* const* d_in, const int* in_sizes, int n_in,
                              void* d_out, int out_size, void* d_ws, size_t ws_size,
                              hipStream_t stream) {
    const float* x    = (const float*)d_in[0];
    const float* wqkv = (const float*)d_in[1];
    const float* bqkv = (const float*)d_in[2];
    const float* wout = (const float*)d_in[3];
    const float* bout = (const float*)d_in[4];
    const int*   win  = (const int*)d_in[5];
    float* out = (float*)d_out;

    u16* xb    = (u16*)d_ws;
    u16* wqkvb = xb    + 8192ull * 512;
    u16* woutb = wqkvb + 1536ull * 512;
    u16* qkvb  = woutb + 512ull * 512;
    u16* ctxb  = qkvb  + 3ull * 16 * 4096 * 64;

    k_cast_all<<<5120, 256, 0, stream>>>(x, wqkv, wout, xb, wqkvb, woutb);
    k_gemm_qkv<<<dim3(64, 12), 256, 0, stream>>>(xb, wqkvb, bqkv, qkvb);
    k_attn<<<dim3(64, 16), 128, 0, stream>>>(qkvb, qkvb + 16ull * 4096 * 64,
                                             qkvb + 32ull * 4096 * 64, ctxb, win);
    k_gemm_out<<<dim3(64, 8), 256, 0, stream>>>(ctxb, woutb, bout, out);
}

// Round 9
// 198.667 us; speedup vs baseline: 1.4949x; 1.0752x over previous
//
#include <hip/hip_runtime.h>
#include <hip/hip_bf16.h>

typedef unsigned short u16;
typedef __bf16 bf16x8 __attribute__((ext_vector_type(8)));
typedef float f32x4 __attribute__((ext_vector_type(4)));

__device__ __forceinline__ f32x4 mfma16(bf16x8 a, bf16x8 b, f32x4 c) {
    return __builtin_amdgcn_mfma_f32_16x16x32_bf16(a, b, c, 0, 0, 0);
}

// fp32 -> bf16 bits, round-to-nearest-even
__device__ __forceinline__ u16 f2b(float x) {
    union { float f; unsigned u; } a; a.f = x;
    unsigned r = a.u + 0x7fffu + ((a.u >> 16) & 1u);
    return (u16)(r >> 16);
}
__device__ __forceinline__ unsigned f2b2(float a, float b) {
    union { __hip_bfloat162 h; unsigned u; } cv;
    cv.h = __float22bfloat162_rn(make_float2(a, b));
    return cv.u;
}
// async 16B global -> LDS (DMA, vmcnt-tracked)
__device__ __forceinline__ void async16(const u16* g, u16* l) {
    __builtin_amdgcn_global_load_lds((const __attribute__((address_space(1))) unsigned int*)g,
                                     (__attribute__((address_space(3))) unsigned int*)l, 16, 0, 0);
}

// ---------------- fused cast fp32 -> bf16 for all three inputs ----------------
#define NX  (8192 * 512)
#define NWQ (1536 * 512)
#define NWO (512 * 512)
__global__ __launch_bounds__(256) void k_cast_all(const float* __restrict__ x,
                                                  const float* __restrict__ wq,
                                                  const float* __restrict__ wo,
                                                  u16* __restrict__ xb,
                                                  u16* __restrict__ wqb,
                                                  u16* __restrict__ wob) {
    int i = (blockIdx.x * 256 + threadIdx.x) * 4;
    const float* s; u16* d; int off;
    if (i < NX)            { s = x;  d = xb;  off = i; }
    else if (i < NX + NWQ) { s = wq; d = wqb; off = i - NX; }
    else                   { s = wo; d = wob; off = i - NX - NWQ; }
    float4 f = *(const float4*)&s[off];
    uint2 o = make_uint2(f2b2(f.x, f.y), f2b2(f.z, f.w));
    *(uint2*)&d[off] = o;
}

// ---------------- QKV GEMM (async-DMA double-buffered) -----------------------
// q -> [B*H][S][64] bf16 (pre-scaled 0.125/ln2)
// k -> KF[bh][kt][kg][t][h][quad][l15][8]  (permuted QK A-frag order:
//        key = kt*64+kg*32+8*(l15>>2)+4t+(l15&3), d = h*32+quad*8+j)
// v -> VF[bh][kt][kg][mb][quad][l15][8]    (K=32 PV A-frag order:
//        key = kt*64+kg*32+quad*8+j, d = mb*16+l15)
__global__ __launch_bounds__(256, 3) void k_gemm_qkv(const u16* __restrict__ xb,
                                                     const u16* __restrict__ wb,
                                                     const float* __restrict__ bias,
                                                     u16* __restrict__ qkvout) {
    __shared__ u16 AL[2][4096];
    __shared__ u16 WL[2][4096];
    const int tid = threadIdx.x;
    const int w = tid >> 6, lane = tid & 63, l15 = lane & 15, quad = lane >> 4;
    const int mb = blockIdx.x * 128, nb = blockIdx.y * 128;

    f32x4 acc[2][8];
#pragma unroll
    for (int i = 0; i < 2; i++)
#pragma unroll
        for (int j = 0; j < 8; j++) acc[i][j] = (f32x4){0.f, 0.f, 0.f, 0.f};

    const u16* agp = xb + (size_t)(mb + w * 32 + (lane >> 2)) * 512 + (lane & 3) * 8;
    const u16* wgp = wb + (size_t)(nb + w * 32 + (lane >> 2)) * 512 + (lane & 3) * 8;
    const int ldst = w * 1024 + lane * 8;

    async16(agp, &AL[0][ldst]);
    async16(agp + 16 * 512, &AL[0][ldst + 512]);
    async16(wgp, &WL[0][ldst]);
    async16(wgp + 16 * 512, &WL[0][ldst + 512]);
    __syncthreads();
    int p = 0;
    for (int ks = 0; ks < 16; ks++) {
        if (ks < 15) {
            int k0n = (ks + 1) * 32;
            async16(agp + k0n, &AL[p ^ 1][ldst]);
            async16(agp + 16 * 512 + k0n, &AL[p ^ 1][ldst + 512]);
            async16(wgp + k0n, &WL[p ^ 1][ldst]);
            async16(wgp + 16 * 512 + k0n, &WL[p ^ 1][ldst + 512]);
        }
        bf16x8 a0 = *(const bf16x8*)&AL[p][(w * 32 + l15) * 32 + quad * 8];
        bf16x8 a1 = *(const bf16x8*)&AL[p][(w * 32 + 16 + l15) * 32 + quad * 8];
#pragma unroll
        for (int nt = 0; nt < 8; nt++) {
            bf16x8 bfr = *(const bf16x8*)&WL[p][(nt * 16 + l15) * 32 + quad * 8];
            acc[0][nt] = mfma16(a0, bfr, acc[0][nt]);
            acc[1][nt] = mfma16(a1, bfr, acc[1][nt]);
        }
        if (ks < 15) { __syncthreads(); p ^= 1; }
    }
    const int seg = nb >> 9;          // 0=q 1=k 2=v
    u16* obase = qkvout + (size_t)seg * (16ull * 4096 * 64);
    if (seg == 0) {
        const float sc = 0.125f * 1.44269504088896340736f;
#pragma unroll
        for (int mt = 0; mt < 2; mt++)
#pragma unroll
            for (int nt = 0; nt < 8; nt++) {
                int dcol = nb + nt * 16 + l15;
                int hh = (dcol >> 6) & 7, dloc = dcol & 63;
                float bs = bias[dcol];
#pragma unroll
                for (int r = 0; r < 4; r++) {
                    int m = mb + w * 32 + mt * 16 + quad * 4 + r;
                    float vv = (acc[mt][nt][r] + bs) * sc;
                    int b = m >> 12, s = m & 4095;
                    obase[((size_t)((b * 8 + hh) * 4096 + s)) * 64 + dloc] = f2b(vv);
                }
            }
    } else if (seg == 1) {
        // permuted K frag scatter
#pragma unroll
        for (int mt = 0; mt < 2; mt++)
#pragma unroll
            for (int nt = 0; nt < 8; nt++) {
                int dcol = nb + nt * 16 + l15;
                int hh = (dcol >> 6) & 7, d = dcol & 63;
                int h2 = d >> 5, qk = (d >> 3) & 3, j = d & 7;
                float bs = bias[dcol];
                int m0 = mb + w * 32 + mt * 16 + quad * 4;
                int b = m0 >> 12, s0 = m0 & 4095;
                int kt = s0 >> 6, ksx = s0 & 63;
                int kg2 = ksx >> 5, rem = ksx & 31;
                int t2 = (rem >> 2) & 1, lb = (rem >> 3) * 4;   // l15k = lb + r
                size_t base = ((((((size_t)(b * 8 + hh) * 64 + kt) * 2 + kg2) * 2 + t2) * 2 + h2) * 4 + qk) * 16 + lb;
#pragma unroll
                for (int r = 0; r < 4; r++)
                    obase[(base + r) * 8 + j] = f2b(acc[mt][nt][r] + bs);
            }
    } else {
        // V frag scatter (K=32 A-operand order)
#pragma unroll
        for (int mt = 0; mt < 2; mt++)
#pragma unroll
            for (int nt = 0; nt < 8; nt++) {
                int c = nb + nt * 16 + l15;
                int hh = (c >> 6) & 7, d = c & 63;
                int mbv = d >> 4, l15v = d & 15;
                float bs = bias[c];
                int m0 = mb + w * 32 + mt * 16 + quad * 4;
                int b = m0 >> 12, si = m0 & 4095;
                int kt = si >> 6, ksx = si & 63;
                int kg2 = ksx >> 5, qv = (ksx >> 3) & 3, j0 = ksx & 7;
                uint2 o = make_uint2(f2b2(acc[mt][nt][0] + bs, acc[mt][nt][1] + bs),
                                     f2b2(acc[mt][nt][2] + bs, acc[mt][nt][3] + bs));
                size_t F = (((((size_t)(b * 8 + hh) * 64 + kt) * 2 + kg2) * 4 + mbv) * 4 + qv) * 16 + l15v;
                *(uint2*)&obase[F * 8 + j0] = o;
            }
    }
}

// ---------------- flash attention v9 (inverted-window mask) -----------------
// 256 thr = 4 waves x 32 q-rows (128-row block, staging shared by 4 waves).
// K,V pre-scattered to permuted MFMA frag order; DMA double-buffer, one
// barrier/iter, prefetch a full compute-phase ahead. All MFMAs are K=32
// full-rate 16x16x32: QK 16 + PV 16 + ones-lsum 4 per tile.
__global__ __launch_bounds__(256, 2) void k_attn(const u16* __restrict__ qg,
                                                 const u16* __restrict__ kfg,
                                                 const u16* __restrict__ vfg,
                                                 u16* __restrict__ ctx,
                                                 const int* __restrict__ win) {
    __shared__ u16 KL[2][4096];
    __shared__ u16 VL[2][4096];
    const int tid = threadIdx.x;
    const int w = tid >> 6, lane = tid & 63, l15 = lane & 15, quad = lane >> 4;
    const int bh = blockIdx.y;
    const int qb0 = blockIdx.x * 128;
    const int qb0w = qb0 + w * 32;
    const int W = win[0];
    const size_t bhb = (size_t)bh * 4096 * 64;

    bf16x8 qf[2][2];
#pragma unroll
    for (int g = 0; g < 2; g++) {
        const u16* qrow = &qg[bhb + (size_t)(qb0w + g * 16 + l15) * 64];
        qf[g][0] = *(const bf16x8*)&qrow[quad * 8];
        qf[g][1] = *(const bf16x8*)&qrow[32 + quad * 8];
    }
    bf16x8 ones8;
    {
        u16 v = (l15 == 0) ? (u16)0x3F80 : (u16)0;
        union { u16 a[8]; bf16x8 b; } c;
#pragma unroll
        for (int i = 0; i < 8; i++) c.a[i] = v;
        ones8 = c.b;
    }

    f32x4 O[2][4];
#pragma unroll
    for (int g = 0; g < 2; g++)
#pragma unroll
        for (int mb = 0; mb < 4; mb++) O[g][mb] = (f32x4){0.f, 0.f, 0.f, 0.f};
    f32x4 O1[2] = {(f32x4){0.f, 0.f, 0.f, 0.f}, (f32x4){0.f, 0.f, 0.f, 0.f}};

    const u16* kbase = kfg + bhb;   // [kt][4096]
    const u16* vbase = vfg + bhb;
    const int soff = w * 1024 + lane * 8;

    auto skip = [&](int kb) { return max(qb0 + 127 - kb, kb + 63 - qb0) <= W; };
    int kb = 0;
    while (kb < 4096 && skip(kb)) kb += 64;
    {
        const u16* kt_p = kbase + (size_t)(kb >> 6) * 4096;
        const u16* vt_p = vbase + (size_t)(kb >> 6) * 4096;
        async16(kt_p + soff, &KL[0][soff]);
        async16(kt_p + soff + 512, &KL[0][soff + 512]);
        async16(vt_p + soff, &VL[0][soff]);
        async16(vt_p + soff + 512, &VL[0][soff + 512]);
    }
    __syncthreads();
    int p = 0;
    while (kb < 4096) {
        int kb_next = kb + 64;
        while (kb_next < 4096 && skip(kb_next)) kb_next += 64;
        if (kb_next < 4096) {
            const u16* kt_p = kbase + (size_t)(kb_next >> 6) * 4096;
            const u16* vt_p = vbase + (size_t)(kb_next >> 6) * 4096;
            async16(kt_p + soff, &KL[p ^ 1][soff]);
            async16(kt_p + soff + 512, &KL[p ^ 1][soff + 512]);
            async16(vt_p + soff, &VL[p ^ 1][soff]);
            async16(vt_p + soff + 512, &VL[p ^ 1][soff + 512]);
        }
        const bool partial = (kb + 63 >= qb0 - W) && (kb <= qb0 + 127 + W);
        // K frags [kg][t][h], V frags [kg][mb] — all b128, frag-linear
        bf16x8 kf[2][2][2];
#pragma unroll
        for (int kg = 0; kg < 2; kg++)
#pragma unroll
            for (int t = 0; t < 2; t++)
#pragma unroll
                for (int h = 0; h < 2; h++)
                    kf[kg][t][h] = *(const bf16x8*)&KL[p][((((kg * 2 + t) * 2 + h) * 4 + quad) * 16 + l15) * 8];
        bf16x8 vfr[2][4];
#pragma unroll
        for (int kg = 0; kg < 2; kg++)
#pragma unroll
            for (int mb = 0; mb < 4; mb++)
                vfr[kg][mb] = *(const bf16x8*)&VL[p][(((kg * 4 + mb) * 4 + quad) * 16 + l15) * 8];

        // QK: C[g][kg][t] holds keys kb+kg*32+8*quad+4t+r at qrow l15
        f32x4 C[2][2][2];
#pragma unroll
        for (int g = 0; g < 2; g++)
#pragma unroll
            for (int kg = 0; kg < 2; kg++)
#pragma unroll
                for (int t = 0; t < 2; t++) {
                    f32x4 z = (f32x4){0.f, 0.f, 0.f, 0.f};
                    C[g][kg][t] = mfma16(kf[kg][t][0], qf[g][0], z);
                    C[g][kg][t] = mfma16(kf[kg][t][1], qf[g][1], C[g][kg][t]);
                }
        // exp + pack into K=32 B-frags (k = quad*8 + j)
        bf16x8 pb[2][2];
        if (!partial) {
#pragma unroll
            for (int g = 0; g < 2; g++)
#pragma unroll
                for (int kg = 0; kg < 2; kg++) {
                    float p0 = __builtin_amdgcn_exp2f(C[g][kg][0][0]);
                    float p1 = __builtin_amdgcn_exp2f(C[g][kg][0][1]);
                    float p2 = __builtin_amdgcn_exp2f(C[g][kg][0][2]);
                    float p3 = __builtin_amdgcn_exp2f(C[g][kg][0][3]);
                    float p4 = __builtin_amdgcn_exp2f(C[g][kg][1][0]);
                    float p5 = __builtin_amdgcn_exp2f(C[g][kg][1][1]);
                    float p6 = __builtin_amdgcn_exp2f(C[g][kg][1][2]);
                    float p7 = __builtin_amdgcn_exp2f(C[g][kg][1][3]);
                    union { uint4 u; bf16x8 v; } pk;
                    pk.u = make_uint4(f2b2(p0, p1), f2b2(p2, p3), f2b2(p4, p5), f2b2(p6, p7));
                    pb[g][kg] = pk.v;
                }
        } else {
#pragma unroll
            for (int g = 0; g < 2; g++) {
                int qr = qb0w + g * 16 + l15;
#pragma unroll
                for (int kg = 0; kg < 2; kg++) {
                    float pv[8];
#pragma unroll
                    for (int t = 0; t < 2; t++)
#pragma unroll
                        for (int r = 0; r < 4; r++) {
                            int key = kb + kg * 32 + 8 * quad + 4 * t + r;
                            int dd = qr - key; dd = dd < 0 ? -dd : dd;
                            pv[t * 4 + r] = (dd <= W) ? 0.f
                                          : __builtin_amdgcn_exp2f(C[g][kg][t][r]);
                        }
                    union { uint4 u; bf16x8 v; } pk;
                    pk.u = make_uint4(f2b2(pv[0], pv[1]), f2b2(pv[2], pv[3]),
                                      f2b2(pv[4], pv[5]), f2b2(pv[6], pv[7]));
                    pb[g][kg] = pk.v;
                }
            }
        }
        // PV (K=32 full-rate) + ones-lsum
#pragma unroll
        for (int kg = 0; kg < 2; kg++)
#pragma unroll
            for (int g = 0; g < 2; g++) {
#pragma unroll
                for (int mb = 0; mb < 4; mb++)
                    O[g][mb] = mfma16(vfr[kg][mb], pb[g][kg], O[g][mb]);
                O1[g] = mfma16(ones8, pb[g][kg], O1[g]);
            }
        if (kb_next < 4096) { __syncthreads(); p ^= 1; }
        kb = kb_next;
    }
    int b = bh >> 3, h = bh & 7;
#pragma unroll
    for (int g = 0; g < 2; g++) {
        float ls = __shfl(O1[g][0], l15);
        float inv = 1.0f / ls;
        int qr = qb0w + g * 16 + l15;
        size_t rowoff = ((size_t)(b * 4096 + qr)) * 512 + h * 64;
#pragma unroll
        for (int mb = 0; mb < 4; mb++) {
            uint2 o = make_uint2(f2b2(O[g][mb][0] * inv, O[g][mb][1] * inv),
                                 f2b2(O[g][mb][2] * inv, O[g][mb][3] * inv));
            *(uint2*)&ctx[rowoff + mb * 16 + quad * 4] = o;
        }
    }
}

// ---------------- out GEMM (async-DMA double-buffered) -----------------------
__global__ __launch_bounds__(256, 2) void k_gemm_out(const u16* __restrict__ ab,
                                                     const u16* __restrict__ wb,
                                                     const float* __restrict__ bias,
                                                     float* __restrict__ out) {
    __shared__ u16 AL[2][4096];
    __shared__ u16 WL[2][2048];
    const int tid = threadIdx.x;
    const int w = tid >> 6, lane = tid & 63, l15 = lane & 15, quad = lane >> 4;
    const int mb = blockIdx.x * 128, nb = blockIdx.y * 64;

    f32x4 acc[2][4];
#pragma unroll
    for (int i = 0; i < 2; i++)
#pragma unroll
        for (int j = 0; j < 4; j++) acc[i][j] = (f32x4){0.f, 0.f, 0.f, 0.f};

    const u16* agp = ab + (size_t)(mb + w * 32 + (lane >> 2)) * 512 + (lane & 3) * 8;
    const u16* wgp = wb + (size_t)(nb + w * 16 + (lane >> 2)) * 512 + (lane & 3) * 8;
    const int ldstA = w * 1024 + lane * 8;
    const int ldstW = w * 512 + lane * 8;

    async16(agp, &AL[0][ldstA]);
    async16(agp + 16 * 512, &AL[0][ldstA + 512]);
    async16(wgp, &WL[0][ldstW]);
    __syncthreads();
    int p = 0;
    for (int ks = 0; ks < 16; ks++) {
        if (ks < 15) {
            int k0n = (ks + 1) * 32;
            async16(agp + k0n, &AL[p ^ 1][ldstA]);
            async16(agp + 16 * 512 + k0n, &AL[p ^ 1][ldstA + 512]);
            async16(wgp + k0n, &WL[p ^ 1][ldstW]);
        }
        bf16x8 a0 = *(const bf16x8*)&AL[p][(w * 32 + l15) * 32 + quad * 8];
        bf16x8 a1 = *(const bf16x8*)&AL[p][(w * 32 + 16 + l15) * 32 + quad * 8];
#pragma unroll
        for (int nt = 0; nt < 4; nt++) {
            bf16x8 bfr = *(const bf16x8*)&WL[p][(nt * 16 + l15) * 32 + quad * 8];
            acc[0][nt] = mfma16(a0, bfr, acc[0][nt]);
            acc[1][nt] = mfma16(a1, bfr, acc[1][nt]);
        }
        if (ks < 15) { __syncthreads(); p ^= 1; }
    }
#pragma unroll
    for (int mt = 0; mt < 2; mt++)
#pragma unroll
        for (int nt = 0; nt < 4; nt++) {
            int n = nb + nt * 16 + l15;
            float bs = bias[n];
#pragma unroll
            for (int r = 0; r < 4; r++) {
                int m = mb + w * 32 + mt * 16 + quad * 4 + r;
                out[(size_t)m * 512 + n] = acc[mt][nt][r] + bs;
            }
        }
}

extern "C" void kernel_launch(void* const* d_in, const int* in_sizes, int n_in,
                              void* d_out, int out_size, void* d_ws, size_t ws_size,
                              hipStream_t stream) {
    const float* x    = (const float*)d_in[0];
    const float* wqkv = (const float*)d_in[1];
    const float* bqkv = (const float*)d_in[2];
    const float* wout = (const float*)d_in[3];
    const float* bout = (const float*)d_in[4];
    const int*   win  = (const int*)d_in[5];
    float* out = (float*)d_out;

    u16* xb    = (u16*)d_ws;
    u16* wqkvb = xb    + 8192ull * 512;
    u16* woutb = wqkvb + 1536ull * 512;
    u16* qkvb  = woutb + 512ull * 512;
    u16* ctxb  = qkvb  + 3ull * 16 * 4096 * 64;

    k_cast_all<<<5120, 256, 0, stream>>>(x, wqkv, wout, xb, wqkvb, woutb);
    k_gemm_qkv<<<dim3(64, 12), 256, 0, stream>>>(xb, wqkvb, bqkv, qkvb);
    k_attn<<<dim3(32, 16), 256, 0, stream>>>(qkvb, qkvb + 16ull * 4096 * 64,
                                             qkvb + 32ull * 4096 * 64, ctxb, win);
    k_gemm_out<<<dim3(64, 8), 256, 0, stream>>>(ctxb, woutb, bout, out);
}